// Round 5
// baseline (2988.101 us; speedup 1.0000x reference)
//
#include <hip/hip_runtime.h>
#include <math.h>

// Problem constants: B=256, T=512, D=128, H=128 (3H=384), U=64, A=10, LAMDA=0.5
#define B_ 256
#define T_ 512
#define D_ 128
#define H_ 128
#define BH_ 32768      // B_*H_
#define NG 1308160     // 511*256*10 gumbels per agent

// LDS-ordering-only barrier: skips the vmcnt(0) drain __syncthreads() forces.
__device__ __forceinline__ void bar_lds() {
  asm volatile("s_waitcnt lgkmcnt(0)\n\ts_barrier" ::: "memory");
}

// quad reductions on the VALU pipe (DPP), not the LDS pipe (ds_bpermute)
__device__ __forceinline__ float dpp_add_xor1(float v) {
  int r = __builtin_amdgcn_update_dpp(0, __float_as_int(v), 0xB1, 0xF, 0xF, true);
  return v + __int_as_float(r);
}
__device__ __forceinline__ float dpp_add_xor2(float v) {
  int r = __builtin_amdgcn_update_dpp(0, __float_as_int(v), 0x4E, 0xF, 0xF, true);
  return v + __int_as_float(r);
}

// ---------------- threefry2x32 (exact JAX semantics) ----------------
__device__ __forceinline__ void tf2x32(unsigned k0, unsigned k1, unsigned x0, unsigned x1,
                                       unsigned& o0, unsigned& o1) {
  unsigned k2 = k0 ^ k1 ^ 0x1BD11BDAu;
  unsigned v0 = x0 + k0, v1 = x1 + k1;
#define TFR(r) { v0 += v1; v1 = (v1 << (r)) | (v1 >> (32 - (r))); v1 ^= v0; }
  TFR(13) TFR(15) TFR(26) TFR(6)   v0 += k1; v1 += k2 + 1u;
  TFR(17) TFR(29) TFR(16) TFR(24)  v0 += k2; v1 += k0 + 2u;
  TFR(13) TFR(15) TFR(26) TFR(6)   v0 += k0; v1 += k1 + 3u;
  TFR(17) TFR(29) TFR(16) TFR(24)  v0 += k1; v1 += k2 + 4u;
  TFR(13) TFR(15) TFR(26) TFR(6)   v0 += k2; v1 += k0 + 5u;
#undef TFR
  o0 = v0; o1 = v1;
}

__device__ __forceinline__ float gumbel_f(unsigned bits) {
  const float tiny = 1.17549435e-38f;
  float u = __uint_as_float((bits >> 9) | 0x3f800000u) - 1.0f;
  u = u + tiny;
  u = fmaxf(tiny, u);
  return -logf(-logf(u));
}

// ---------------- P0: split keys (jax_threefry_partitionable=True) ----------------
__global__ void p0_keys(unsigned* __restrict__ keys_tab) {
  int i = blockIdx.x * blockDim.x + threadIdx.x;
  if (i >= 1024) return;
  unsigned o0, o1;
  tf2x32(0u, 42u, 0u, (unsigned)i, o0, o1);
  keys_tab[2 * i] = o0; keys_tab[2 * i + 1] = o1;
}

// ---------------- G: fused gi GEMM + agent-2 actions + g1 gumbel table ----------------
// thread <-> (b,t) row. x row in VGPRs (coalesced); W rows via wave-uniform
// scalar-cache loads. Writes gi[bt][0:384], a2_tab, g1 table.
__global__ __launch_bounds__(256, 2) void gemm_fused(
    const float* __restrict__ x, const float* __restrict__ w_ih, const float* __restrict__ b_ih,
    const float* __restrict__ a2w1, const float* __restrict__ a2b1,
    const float* __restrict__ a2w2, const float* __restrict__ a2b2,
    const unsigned* __restrict__ keys_tab,
    float* __restrict__ gi, float* __restrict__ g1, int* __restrict__ a2_tab) {
  const int tid = threadIdx.x;
  const size_t bt = (size_t)blockIdx.x * 256 + tid;
  const int b = (int)(bt >> 9), t = (int)(bt & 511);
  float4 xr[32];
  const float4* xg = (const float4*)(x + bt * 128);
  #pragma unroll
  for (int c = 0; c < 32; c++) xr[c] = xg[c];
  // ---- gi = x @ w_ih.T + b_ih ----
  float* gout = gi + bt * 384;
  for (int r4 = 0; r4 < 96; r4++) {
    float res[4];
    #pragma unroll
    for (int sub = 0; sub < 4; sub++) {
      int r = 4 * r4 + sub;
      const float4* wrow = (const float4*)(w_ih + (size_t)r * 128);  // uniform
      float ax = 0.f, ay = 0.f, az = 0.f, aw = 0.f;
      #pragma unroll
      for (int c = 0; c < 32; c++) {
        float4 w4 = wrow[c];
        ax += w4.x * xr[c].x; ay += w4.y * xr[c].y;
        az += w4.z * xr[c].z; aw += w4.w * xr[c].w;
      }
      res[sub] = ((ax + ay) + (az + aw)) + b_ih[r];
    }
    float4 o; o.x = res[0]; o.y = res[1]; o.z = res[2]; o.w = res[3];
    ((float4*)gout)[r4] = o;
  }
  // ---- a2 hidden layer: z = tanh(x @ a2w1.T + a2b1) ----
  float z[64];
  for (int j4 = 0; j4 < 16; j4++) {
    #pragma unroll
    for (int sub = 0; sub < 4; sub++) {
      int j = 4 * j4 + sub;
      const float4* wrow = (const float4*)(a2w1 + (size_t)j * 128);  // uniform
      float ax = 0.f, ay = 0.f, az = 0.f, aw = 0.f;
      #pragma unroll
      for (int c = 0; c < 32; c++) {
        float4 w4 = wrow[c];
        ax += w4.x * xr[c].x; ay += w4.y * xr[c].y;
        az += w4.z * xr[c].z; aw += w4.w * xr[c].w;
      }
      z[j] = tanhf(((ax + ay) + (az + aw)) + a2b1[j]);
    }
  }
  if (t == 0) return;   // samples exist only for t=1..511
  unsigned k0g = keys_tab[2 * (2 * t)],     k1g = keys_tab[2 * (2 * t) + 1];      // agent1
  unsigned k0a = keys_tab[2 * (2 * t + 1)], k1a = keys_tab[2 * (2 * t + 1) + 1];  // agent2
  float best = 0.f; int bi = 0;
  float g1v[10];
  #pragma unroll 1
  for (int a = 0; a < 10; a++) {
    const float4* wrow = (const float4*)(a2w2 + (size_t)a * 64);  // uniform
    float acc = 0.f;
    #pragma unroll
    for (int c = 0; c < 16; c++) {
      float4 w4 = wrow[c];
      acc += w4.x * z[4 * c] + w4.y * z[4 * c + 1] + w4.z * z[4 * c + 2] + w4.w * z[4 * c + 3];
    }
    unsigned f = (unsigned)(b * 10 + a);
    unsigned o0, o1;
    tf2x32(k0a, k1a, 0u, f, o0, o1);
    float v = (acc + a2b2[a]) + gumbel_f(o0 ^ o1);
    if (a == 0 || v > best) { best = v; bi = a; }
    tf2x32(k0g, k1g, 0u, f, o0, o1);
    g1v[a] = gumbel_f(o0 ^ o1);
  }
  a2_tab[(size_t)(t - 1) * 256 + b] = bi;
  float* g1o = g1 + ((size_t)(t - 1) * 256 + b) * 10;
  #pragma unroll
  for (int a = 0; a < 10; a++) g1o[a] = g1v[a];
}

// ---------------- S: sequential per-batch kernel (1 block = 1 batch elem) ----------------
__global__ __launch_bounds__(512, 2) void seq_kernel(
    const float* __restrict__ gi_glob, const int* __restrict__ mask,
    const float* __restrict__ w_hh, const float* __restrict__ b_hh,
    const float* __restrict__ a1w1, const float* __restrict__ a1b1,
    const float* __restrict__ a1w2, const float* __restrict__ a1b2,
    const float* __restrict__ g1_tab, const int* __restrict__ a2_tab,
    float* __restrict__ out) {
  __shared__ __align__(16) float ring2[20][128];  // doubled ring: h_s at [s%10] and [s%10+10]
  __shared__ __align__(16) float yc[10][384];     // yc[s] = W_hh · ring[s]
  __shared__ __align__(16) float hbuf[128];       // h_{t-1}
  __shared__ __align__(16) float ghi[384];        // staged gi[b][t] (+b_hh on rows 0..255)
  __shared__ __align__(16) float obs[128];        // mean of ring (computed in gates phase)
  __shared__ __align__(16) float z1buf[64];
  __shared__ __align__(16) float lastbuf[128];
  __shared__ __align__(16) float w2buf[10][64];
  __shared__ float bhh3s[128];                    // b_hh rows 256..383 (n-gate, multiplied by r)
  __shared__ float b1s[64], b2s[10];
  __shared__ float g1buf[10];
  __shared__ float2 pl2[16];                      // .x = p(m<32)+b2 ; .y = p(m>=32)+gumbel
  __shared__ int a2s_lds;
  __shared__ int redi[8];
  __shared__ int last_s;

  const int tid = threadIdx.x;
  const int wave = tid >> 6, lane = tid & 63;
  const int b = blockIdx.x;

  // ---- register-resident W_hh for waves 0-5: quad-interleaved k-split ----
  float4 wr[4][8];
  const int q = tid >> 2, qk = tid & 3;
  if (tid < 384) {
    #pragma unroll
    for (int i = 0; i < 4; i++) {
      const float* basep = w_hh + (size_t)(q + 96 * i) * 128 + 4 * qk;
      #pragma unroll
      for (int c = 0; c < 8; c++) wr[i][c] = *(const float4*)(basep + 16 * c);
    }
  }
  // ---- register-resident a1w1 for waves 6/7: lane (m=half-row, kc=half) ----
  float4 w1reg[16];
  float4 bhh4a = make_float4(0.f, 0.f, 0.f, 0.f);
  if (wave >= 6) {
    int m = ((wave - 6) << 5) + (lane >> 1);
    int kc = lane & 1;
    const float4* wp = (const float4*)(a1w1 + (size_t)m * 128 + 64 * kc);
    #pragma unroll
    for (int c = 0; c < 16; c++) w1reg[c] = wp[c];
  }
  if (wave == 6) bhh4a = ((const float4*)b_hh)[lane];   // rows 4*lane..+3 (0..255)

  // ---- LDS init ----
  for (int idx = tid; idx < 2560; idx += 512) ((float*)ring2)[idx] = 0.f;
  for (int idx = tid; idx < 3840; idx += 512) ((float*)yc)[idx] = 0.f;
  for (int idx = tid; idx < 640; idx += 512) w2buf[idx >> 6][idx & 63] = a1w2[idx];
  if (tid < 128) bhh3s[tid] = b_hh[256 + tid];
  if (tid < 64) b1s[tid] = a1b1[tid];
  if (tid < 10) b2s[tid] = a1b2[tid];
  int mv = mask[(size_t)b * T_ + tid];
  #pragma unroll
  for (int off = 1; off < 64; off <<= 1) mv += __shfl_xor(mv, off);
  if (lane == 0) redi[wave] = mv;
  const float4* gi4 = (const float4*)gi_glob;
  float4 gir0 = make_float4(0.f, 0.f, 0.f, 0.f), gir1 = gir0;
  if (wave == 6) {
    size_t base1 = ((size_t)b * 512 + 1) * 96;
    gir0 = gi4[base1 + lane];
    if (lane < 32) gir1 = gi4[base1 + 64 + lane];
  }
  float g1r = 0.f; int a2r = 0;
  if (wave == 7 && lane < 10) g1r = g1_tab[(size_t)b * 10 + lane];
  if (wave == 7 && lane == 12) a2r = a2_tab[b];
  __syncthreads();
  if (tid == 0) {
    int s = 0;
    #pragma unroll
    for (int w = 0; w < 8; w++) s += redi[w];
    last_s = s - 1;
  }
  __syncthreads();
  const int last = last_s;

  // ---- t = 0: h0 = gru(x0, 0); also obs for t=1 (= h0/10, exact order) ----
  if (tid < 128) {
    int j = tid;
    const float* g0 = gi_glob + (size_t)b * 512 * 384;
    float ir = g0[j] + b_hh[j];
    float iz = g0[128 + j] + b_hh[128 + j];
    float in_ = g0[256 + j];
    float hn = b_hh[256 + j];
    float r  = 1.0f / (1.0f + expf(-ir));
    float zz = 1.0f / (1.0f + expf(-iz));
    float n  = tanhf(in_ + r * hn);
    float hnew = (1.0f - zz) * n;
    hbuf[j] = hnew; ring2[0][j] = hnew; ring2[10][j] = hnew;
    obs[j] = hnew / 10.0f;
    if (0 == last) lastbuf[j] = hnew;
  }
  __syncthreads();

  // ---- t = 1..511 ----
  #pragma unroll 1
  for (int t = 1; t < T_; t++) {
    const int sn = (t + 9) % 10;   // slot of h_{t-1}
    if (tid < 384) {
      // ---- yc[sn] = W_hh · h_{t-1} ----
      const float4* hb4 = (const float4*)hbuf;
      float4 a0 = make_float4(0.f, 0.f, 0.f, 0.f), a1v = a0, a2v = a0, a3v = a0;
      #pragma unroll
      for (int c = 0; c < 8; c++) {
        float4 h4 = hb4[4 * c + qk];
        a0.x += wr[0][c].x * h4.x; a0.y += wr[0][c].y * h4.y; a0.z += wr[0][c].z * h4.z; a0.w += wr[0][c].w * h4.w;
        a1v.x += wr[1][c].x * h4.x; a1v.y += wr[1][c].y * h4.y; a1v.z += wr[1][c].z * h4.z; a1v.w += wr[1][c].w * h4.w;
        a2v.x += wr[2][c].x * h4.x; a2v.y += wr[2][c].y * h4.y; a2v.z += wr[2][c].z * h4.z; a2v.w += wr[2][c].w * h4.w;
        a3v.x += wr[3][c].x * h4.x; a3v.y += wr[3][c].y * h4.y; a3v.z += wr[3][c].z * h4.z; a3v.w += wr[3][c].w * h4.w;
      }
      float s0  = (a0.x + a0.y) + (a0.z + a0.w);
      float s1v = (a1v.x + a1v.y) + (a1v.z + a1v.w);
      float s2v = (a2v.x + a2v.y) + (a2v.z + a2v.w);
      float s3v = (a3v.x + a3v.y) + (a3v.z + a3v.w);
      s0  = dpp_add_xor2(dpp_add_xor1(s0));
      s1v = dpp_add_xor2(dpp_add_xor1(s1v));
      s2v = dpp_add_xor2(dpp_add_xor1(s2v));
      s3v = dpp_add_xor2(dpp_add_xor1(s3v));
      float my = (qk == 0) ? s0 : (qk == 1) ? s1v : (qk == 2) ? s2v : s3v;
      yc[sn][q + 96 * qk] = my;
    } else if (wave == 6) {
      // stage ghi (rows 0..255 get +b_hh folded; n-gate rows stay raw)
      float4 g0 = gir0;
      g0.x += bhh4a.x; g0.y += bhh4a.y; g0.z += bhh4a.z; g0.w += bhh4a.w;
      ((float4*)ghi)[lane] = g0;
      if (lane < 32) ((float4*)ghi)[64 + lane] = gir1;
      if (lane < 32)
        *(float4*)(out + BH_ + ((size_t)b * 512 + (t - 1)) * 128 + 4 * lane) =
            *(const float4*)(hbuf + 4 * lane);
      if (t < 511) {
        size_t basep = ((size_t)b * 512 + t + 1) * 96;
        gir0 = gi4[basep + lane];
        if (lane < 32) gir1 = gi4[basep + 64 + lane];
      }
      // z1 rows 0..31 (w1 in registers; obs precomputed last phase)
      {
        int m = lane >> 1, kc = lane & 1;
        float ax = 0.f, ay = 0.f, az = 0.f, aw = 0.f;
        #pragma unroll
        for (int c = 0; c < 16; c++) {
          float4 o4 = ((const float4*)obs)[16 * kc + c];
          ax += w1reg[c].x * o4.x; ay += w1reg[c].y * o4.y;
          az += w1reg[c].z * o4.z; aw += w1reg[c].w * o4.w;
        }
        float d = (ax + ay) + (az + aw);
        d = dpp_add_xor1(d);
        if (kc == 0) z1buf[m] = tanhf(d + b1s[m]);
      }
      if (lane < 40) {
        int a = lane >> 2, k2 = lane & 3;
        int m0 = 8 * k2;
        float4 z4a = ((const float4*)(z1buf + m0))[0], z4b = ((const float4*)(z1buf + m0))[1];
        float4 wa = ((const float4*)(&w2buf[a][m0]))[0], wb = ((const float4*)(&w2buf[a][m0]))[1];
        float p = z4a.x * wa.x + z4a.y * wa.y + z4a.z * wa.z + z4a.w * wa.w
                + z4b.x * wb.x + z4b.y * wb.y + z4b.z * wb.z + z4b.w * wb.w;
        p = dpp_add_xor2(dpp_add_xor1(p));
        if (k2 == 0) pl2[a].x = p + b2s[a];
      }
    } else { // wave 7
      if (lane < 10) g1buf[lane] = g1r;
      if (lane == 12) a2s_lds = a2r;
      if (t < 511) {
        if (lane < 10) g1r = g1_tab[((size_t)t * 256 + b) * 10 + lane];
        if (lane == 12) a2r = a2_tab[(size_t)t * 256 + b];
      }
      // z1 rows 32..63
      {
        int m = 32 + (lane >> 1), kc = lane & 1;
        float ax = 0.f, ay = 0.f, az = 0.f, aw = 0.f;
        #pragma unroll
        for (int c = 0; c < 16; c++) {
          float4 o4 = ((const float4*)obs)[16 * kc + c];
          ax += w1reg[c].x * o4.x; ay += w1reg[c].y * o4.y;
          az += w1reg[c].z * o4.z; aw += w1reg[c].w * o4.w;
        }
        float d = (ax + ay) + (az + aw);
        d = dpp_add_xor1(d);
        if (kc == 0) z1buf[m] = tanhf(d + b1s[m]);
      }
      if (lane < 40) {
        int a = lane >> 2, k2 = lane & 3;
        int m0 = 32 + 8 * k2;
        float4 z4a = ((const float4*)(z1buf + m0))[0], z4b = ((const float4*)(z1buf + m0))[1];
        float4 wa = ((const float4*)(&w2buf[a][m0]))[0], wb = ((const float4*)(&w2buf[a][m0]))[1];
        float p = z4a.x * wa.x + z4a.y * wa.y + z4a.z * wa.z + z4a.w * wa.w
                + z4b.x * wb.x + z4b.y * wb.y + z4b.z * wb.z + z4b.w * wb.w;
        p = dpp_add_xor2(dpp_add_xor1(p));
        if (k2 == 0) pl2[a].y = p + g1buf[a];
      }
    }
    bar_lds();   // ycache/ghi/pl2/a2s ready

    if (tid < 128) {
      // argmax (gate waves only)
      float best = 0.f; int bi = 0;
      #pragma unroll
      for (int a = 0; a < 10; a++) {
        float2 pv = pl2[a];
        float v = pv.x + pv.y;
        if (a == 0 || v > best) { best = v; bi = a; }
      }
      const int s1 = (t + bi) % 10;
      const int s2 = (t + a2s_lds) % 10;
      int j = tid;
      float gh1 = 0.5f * (0.5f * (yc[s1][j]       + yc[s2][j]))       + 0.5f * yc[sn][j];
      float gh2 = 0.5f * (0.5f * (yc[s1][128 + j] + yc[s2][128 + j])) + 0.5f * yc[sn][128 + j];
      float gh3 = bhh3s[j] + 0.5f * (0.5f * (yc[s1][256 + j] + yc[s2][256 + j])) + 0.5f * yc[sn][256 + j];
      float r  = 1.0f / (1.0f + expf(-(ghi[j] + gh1)));
      float zz = 1.0f / (1.0f + expf(-(ghi[128 + j] + gh2)));
      float n  = tanhf(ghi[256 + j] + r * gh3);
      float hw = 0.5f * ((ring2[s1][j] + ring2[s2][j]) * 0.5f) + 0.5f * hbuf[j];
      float hnew = (1.0f - zz) * n + zz * hw;
      hbuf[j] = hnew;
      ring2[t % 10][j] = hnew;
      ring2[t % 10 + 10][j] = hnew;
      if (t == last) lastbuf[j] = hnew;
      // obs for step t+1: exact age order h_{t-9}..h_{t-1} then hnew
      int base = (t + 1) % 10;
      float s = 0.f;
      #pragma unroll
      for (int a = 0; a < 9; a++) s += ring2[base + a][j];
      s += hnew;
      obs[j] = s / 10.0f;
    }
    bar_lds();   // hbuf/ring2/obs ready for next step
  }
  if (tid < 128) {
    out[(size_t)b * H_ + tid] = lastbuf[tid];
    out[BH_ + ((size_t)b * 512 + 511) * 128 + tid] = hbuf[tid];  // h_511
  }
}

extern "C" void kernel_launch(void* const* d_in, const int* in_sizes, int n_in,
                              void* d_out, int out_size, void* d_ws, size_t ws_size,
                              hipStream_t stream) {
  (void)in_sizes; (void)n_in; (void)out_size; (void)ws_size;
  const float* x     = (const float*)d_in[0];
  const int*   mask  = (const int*)d_in[1];
  const float* w_ih  = (const float*)d_in[2];
  const float* w_hh  = (const float*)d_in[3];
  const float* b_ih  = (const float*)d_in[4];
  const float* b_hh  = (const float*)d_in[5];
  const float* a1w1  = (const float*)d_in[6];
  const float* a1b1  = (const float*)d_in[7];
  const float* a1w2  = (const float*)d_in[8];
  const float* a1b2  = (const float*)d_in[9];
  const float* a2w1  = (const float*)d_in[10];
  const float* a2b1  = (const float*)d_in[11];
  const float* a2w2  = (const float*)d_in[12];
  const float* a2b2  = (const float*)d_in[13];
  float* out = (float*)d_out;

  // workspace: gi table (201.3 MB) | g1 (5.2 MB) | keys | a2 actions
  float*    gi       = (float*)d_ws;
  float*    g1       = gi + (size_t)131072 * 384;
  unsigned* keys_tab = (unsigned*)(g1 + NG);
  int*      a2_tab   = (int*)(keys_tab + 2048);

  p0_keys<<<4, 256, 0, stream>>>(keys_tab);
  gemm_fused<<<512, 256, 0, stream>>>(x, w_ih, b_ih, a2w1, a2b1, a2w2, a2b2,
                                      keys_tab, gi, g1, a2_tab);
  seq_kernel<<<256, 512, 0, stream>>>(gi, mask, w_hh, b_hh,
                                      a1w1, a1b1, a1w2, a1b2, g1, a2_tab, out);
}

// Round 6
// 1490.409 us; speedup vs baseline: 2.0049x; 2.0049x over previous
//
#include <hip/hip_runtime.h>
#include <math.h>

// Problem constants: B=256, T=512, D=128, H=128 (3H=384), U=64, A=10, LAMDA=0.5
#define B_ 256
#define T_ 512
#define D_ 128
#define H_ 128
#define BH_ 32768      // B_*H_
#define NG 1308160     // 511*256*10 gumbels per agent

// LDS-ordering-only barrier: skips the vmcnt(0) drain __syncthreads() forces.
__device__ __forceinline__ void bar_lds() {
  asm volatile("s_waitcnt lgkmcnt(0)\n\ts_barrier" ::: "memory");
}

// quad reductions on the VALU pipe (DPP), not the LDS pipe (ds_bpermute)
__device__ __forceinline__ float dpp_add_xor1(float v) {
  int r = __builtin_amdgcn_update_dpp(0, __float_as_int(v), 0xB1, 0xF, 0xF, true);
  return v + __int_as_float(r);
}
__device__ __forceinline__ float dpp_add_xor2(float v) {
  int r = __builtin_amdgcn_update_dpp(0, __float_as_int(v), 0x4E, 0xF, 0xF, true);
  return v + __int_as_float(r);
}

// ---------------- threefry2x32 (exact JAX semantics) ----------------
__device__ __forceinline__ void tf2x32(unsigned k0, unsigned k1, unsigned x0, unsigned x1,
                                       unsigned& o0, unsigned& o1) {
  unsigned k2 = k0 ^ k1 ^ 0x1BD11BDAu;
  unsigned v0 = x0 + k0, v1 = x1 + k1;
#define TFR(r) { v0 += v1; v1 = (v1 << (r)) | (v1 >> (32 - (r))); v1 ^= v0; }
  TFR(13) TFR(15) TFR(26) TFR(6)   v0 += k1; v1 += k2 + 1u;
  TFR(17) TFR(29) TFR(16) TFR(24)  v0 += k2; v1 += k0 + 2u;
  TFR(13) TFR(15) TFR(26) TFR(6)   v0 += k0; v1 += k1 + 3u;
  TFR(17) TFR(29) TFR(16) TFR(24)  v0 += k1; v1 += k2 + 4u;
  TFR(13) TFR(15) TFR(26) TFR(6)   v0 += k2; v1 += k0 + 5u;
#undef TFR
  o0 = v0; o1 = v1;
}

__device__ __forceinline__ float gumbel_f(unsigned bits) {
  const float tiny = 1.17549435e-38f;
  float u = __uint_as_float((bits >> 9) | 0x3f800000u) - 1.0f;
  u = u + tiny;
  u = fmaxf(tiny, u);
  return -logf(-logf(u));
}

// ---------------- P0: split keys (jax_threefry_partitionable=True) ----------------
__global__ void p0_keys(unsigned* __restrict__ keys_tab) {
  int i = blockIdx.x * blockDim.x + threadIdx.x;
  if (i >= 1024) return;
  unsigned o0, o1;
  tf2x32(0u, 42u, 0u, (unsigned)i, o0, o1);
  keys_tab[2 * i] = o0; keys_tab[2 * i + 1] = o1;
}

// ---------------- P3: gumbel table for agent 1 (agent 2 inlined in p2) ----------------
__global__ void p3_gumbel(const unsigned* __restrict__ keys_tab, float* __restrict__ g1) {
  int rem = blockIdx.x * blockDim.x + threadIdx.x;
  if (rem >= NG) return;
  int tm1 = rem / 2560;
  int f = rem - tm1 * 2560;
  int t = tm1 + 1;
  unsigned k0 = keys_tab[2 * (2 * t)], k1 = keys_tab[2 * (2 * t) + 1];
  unsigned b1, b2;
  tf2x32(k0, k1, 0u, (unsigned)f, b1, b2);
  g1[rem] = gumbel_f(b1 ^ b2);
}

// ---------------- P2: agent-2 actions (depend only on x), gumbel inlined ----------------
__global__ __launch_bounds__(256) void p2_a2(const float* __restrict__ x,
    const float* __restrict__ w1, const float* __restrict__ b1,
    const float* __restrict__ w2, const float* __restrict__ b2,
    const unsigned* __restrict__ keys_tab, int* __restrict__ a2_tab) {
  __shared__ float4 w1v[32][64];
  __shared__ __align__(16) float w2s[10][64];
  __shared__ float b1s[64];
  __shared__ float b2s[10];
  __shared__ __align__(16) float zs[4][8][64];
  int tid = threadIdx.x, wv = tid >> 6, lane = tid & 63;
  for (int idx = tid; idx < 2048; idx += 256) {
    int c = idx >> 6, m = idx & 63;
    w1v[c][m] = ((const float4*)(w1 + m * 128))[c];
  }
  for (int idx = tid; idx < 640; idx += 256) w2s[idx >> 6][idx & 63] = w2[idx];
  if (tid < 64) b1s[tid] = b1[tid];
  if (tid < 10) b2s[tid] = b2[tid];
  __syncthreads();
  int s0 = blockIdx.x * 32 + wv * 8;
  int t = (s0 >> 8) + 1;
  unsigned k0 = keys_tab[2 * (2 * t + 1)], k1 = keys_tab[2 * (2 * t + 1) + 1];
  int m = lane;
  for (int pr = 0; pr < 4; pr++) {
    int sA = s0 + 2 * pr, sB = sA + 1;
    int bA = sA & 255, bB = sB & 255;
    const float4* xA = (const float4*)(x + ((size_t)bA * T_ + t) * D_);
    const float4* xB = (const float4*)(x + ((size_t)bB * T_ + t) * D_);
    float accA = 0.f, accB = 0.f;
    #pragma unroll
    for (int c = 0; c < 32; c++) {
      float4 w4 = w1v[c][m];
      float4 xa = xA[c], xb = xB[c];
      accA += w4.x * xa.x + w4.y * xa.y + w4.z * xa.z + w4.w * xa.w;
      accB += w4.x * xb.x + w4.y * xb.y + w4.z * xb.z + w4.w * xb.w;
    }
    zs[wv][2 * pr][m]     = tanhf(accA + b1s[m]);
    zs[wv][2 * pr + 1][m] = tanhf(accB + b1s[m]);
  }
  __syncthreads();
  int a = lane & 15, kc = lane >> 4;
  for (int i = 0; i < 8; i++) {
    int s = s0 + i, b = s & 255;
    float p = 0.f;
    if (a < 10) {
      const float4* zp = (const float4*)(&zs[wv][i][16 * kc]);
      const float4* wp = (const float4*)(&w2s[a][16 * kc]);
      #pragma unroll
      for (int c = 0; c < 4; c++) {
        float4 zv = zp[c], w4 = wp[c];
        p += w4.x * zv.x + w4.y * zv.y + w4.z * zv.z + w4.w * zv.w;
      }
    }
    p += __shfl_xor(p, 16);
    p += __shfl_xor(p, 32);
    float val = -3.0e38f;
    if (a < 10) {
      unsigned bb1, bb2;
      tf2x32(k0, k1, 0u, (unsigned)(b * 10 + a), bb1, bb2);
      val = (p + b2s[a]) + gumbel_f(bb1 ^ bb2);
    }
    float best = 0.f; int bi = 0;
    #pragma unroll
    for (int aa = 0; aa < 10; aa++) {
      float v = __shfl(val, aa);
      if (aa == 0 || v > best) { best = v; bi = aa; }
    }
    if (lane == 0) a2_tab[(size_t)(t - 1) * 256 + b] = bi;
  }
}

// ---------------- G: tiled fp32 GEMM  gi[M,384] = X[M,128]·W^T + b ----------------
// Block tile 256m x 64n, 256 threads, micro 16m x 4n, K staged in 4 chunks of 32.
// LDS k-major with padded strides (264 / 72 floats) -> all ds ops <=2-way (free).
#define SX 264
#define SW 72
__global__ __launch_bounds__(256, 4) void gemm_tiled(
    const float* __restrict__ x, const float* __restrict__ w_ih,
    const float* __restrict__ b_ih, float* __restrict__ gi) {
  __shared__ __align__(16) float Xs[32 * SX];
  __shared__ __align__(16) float Ws[32 * SW];
  const int tid = threadIdx.x;
  const int mb = blockIdx.x & 511;          // 512 m-tiles
  const int nb = blockIdx.x >> 9;           // 6 n-tiles (same W strip for 512 consecutive blocks)
  const size_t m0 = (size_t)mb * 256;
  const int n0 = nb * 64;
  const int mt = tid >> 4;                  // 0..15 -> rows mt*16..+15
  const int nt = tid & 15;                  // 0..15 -> cols nt*4..+3
  const int kg = tid >> 5;                  // staging: k-group 0..7
  const int ri = tid & 31;                  // staging: row-in-pass

  float acc[16][4];
  #pragma unroll
  for (int i = 0; i < 16; i++)
    #pragma unroll
    for (int j = 0; j < 4; j++) acc[i][j] = 0.f;

  #pragma unroll 1
  for (int kc = 0; kc < 4; kc++) {
    const int k0 = kc * 32;
    __syncthreads();
    // stage X chunk: 256 rows x 32 k (transposed to k-major)
    #pragma unroll
    for (int p = 0; p < 8; p++) {
      int row = ri + 32 * p;
      float4 v = *(const float4*)(x + (m0 + row) * 128 + k0 + 4 * kg);
      Xs[(4 * kg + 0) * SX + row] = v.x;
      Xs[(4 * kg + 1) * SX + row] = v.y;
      Xs[(4 * kg + 2) * SX + row] = v.z;
      Xs[(4 * kg + 3) * SX + row] = v.w;
    }
    // stage W chunk: 64 rows x 32 k (transposed)
    #pragma unroll
    for (int p = 0; p < 2; p++) {
      int n = ri + 32 * p;
      float4 v = *(const float4*)(w_ih + (size_t)(n0 + n) * 128 + k0 + 4 * kg);
      Ws[(4 * kg + 0) * SW + n] = v.x;
      Ws[(4 * kg + 1) * SW + n] = v.y;
      Ws[(4 * kg + 2) * SW + n] = v.z;
      Ws[(4 * kg + 3) * SW + n] = v.w;
    }
    __syncthreads();
    // compute
    #pragma unroll 4
    for (int kk = 0; kk < 32; kk++) {
      const float* xrow = Xs + kk * SX + mt * 16;
      float4 xa0 = ((const float4*)xrow)[0];
      float4 xa1 = ((const float4*)xrow)[1];
      float4 xa2 = ((const float4*)xrow)[2];
      float4 xa3 = ((const float4*)xrow)[3];
      float4 wv = *(const float4*)(Ws + kk * SW + nt * 4);
      float xv[16] = {xa0.x, xa0.y, xa0.z, xa0.w, xa1.x, xa1.y, xa1.z, xa1.w,
                      xa2.x, xa2.y, xa2.z, xa2.w, xa3.x, xa3.y, xa3.z, xa3.w};
      #pragma unroll
      for (int i = 0; i < 16; i++) {
        acc[i][0] += xv[i] * wv.x;
        acc[i][1] += xv[i] * wv.y;
        acc[i][2] += xv[i] * wv.z;
        acc[i][3] += xv[i] * wv.w;
      }
    }
  }
  // epilogue: +bias, coalesced float4 stores
  float4 bias = *(const float4*)(b_ih + n0 + nt * 4);
  #pragma unroll
  for (int i = 0; i < 16; i++) {
    float4 o;
    o.x = acc[i][0] + bias.x; o.y = acc[i][1] + bias.y;
    o.z = acc[i][2] + bias.z; o.w = acc[i][3] + bias.w;
    size_t m = m0 + (size_t)mt * 16 + i;
    *(float4*)(gi + m * 384 + n0 + nt * 4) = o;
  }
}

// ---------------- S: sequential per-batch kernel (1 block = 1 batch elem) ----------------
__global__ __launch_bounds__(512, 2) void seq_kernel(
    const float* __restrict__ gi_glob, const int* __restrict__ mask,
    const float* __restrict__ w_hh, const float* __restrict__ b_hh,
    const float* __restrict__ a1w1, const float* __restrict__ a1b1,
    const float* __restrict__ a1w2, const float* __restrict__ a1b2,
    const float* __restrict__ g1_tab, const int* __restrict__ a2_tab,
    float* __restrict__ out) {
  __shared__ __align__(16) float ring2[20][128];  // doubled ring: h_s at [s%10] and [s%10+10]
  __shared__ __align__(16) float yc[10][384];     // yc[s] = W_hh · ring[s]
  __shared__ __align__(16) float hbuf[128];       // h_{t-1}
  __shared__ __align__(16) float ghi[384];        // staged gi[b][t] (+b_hh on rows 0..255)
  __shared__ __align__(16) float obs[128];        // mean of ring (computed in gates phase)
  __shared__ __align__(16) float z1buf[64];
  __shared__ __align__(16) float lastbuf[128];
  __shared__ __align__(16) float w2buf[10][64];
  __shared__ float bhh3s[128];                    // b_hh rows 256..383 (n-gate, multiplied by r)
  __shared__ float b1s[64], b2s[10];
  __shared__ float g1buf[10];
  __shared__ float2 pl2[16];                      // .x = p(m<32)+b2 ; .y = p(m>=32)+gumbel
  __shared__ int a2s_lds;
  __shared__ int redi[8];
  __shared__ int last_s;

  const int tid = threadIdx.x;
  const int wave = tid >> 6, lane = tid & 63;
  const int b = blockIdx.x;

  // ---- register-resident W_hh for waves 0-5: quad-interleaved k-split ----
  float4 wr[4][8];
  const int q = tid >> 2, qk = tid & 3;
  if (tid < 384) {
    #pragma unroll
    for (int i = 0; i < 4; i++) {
      const float* basep = w_hh + (size_t)(q + 96 * i) * 128 + 4 * qk;
      #pragma unroll
      for (int c = 0; c < 8; c++) wr[i][c] = *(const float4*)(basep + 16 * c);
    }
  }
  // ---- register-resident a1w1 for waves 6/7 ----
  float4 w1reg[16];
  float4 bhh4a = make_float4(0.f, 0.f, 0.f, 0.f);
  if (wave >= 6) {
    int m = ((wave - 6) << 5) + (lane >> 1);
    int kc = lane & 1;
    const float4* wp = (const float4*)(a1w1 + (size_t)m * 128 + 64 * kc);
    #pragma unroll
    for (int c = 0; c < 16; c++) w1reg[c] = wp[c];
  }
  if (wave == 6) bhh4a = ((const float4*)b_hh)[lane];   // rows 4*lane..+3 (0..255)

  // ---- LDS init ----
  for (int idx = tid; idx < 2560; idx += 512) ((float*)ring2)[idx] = 0.f;
  for (int idx = tid; idx < 3840; idx += 512) ((float*)yc)[idx] = 0.f;
  for (int idx = tid; idx < 640; idx += 512) w2buf[idx >> 6][idx & 63] = a1w2[idx];
  if (tid < 128) bhh3s[tid] = b_hh[256 + tid];
  if (tid < 64) b1s[tid] = a1b1[tid];
  if (tid < 10) b2s[tid] = a1b2[tid];
  int mv = mask[(size_t)b * T_ + tid];
  #pragma unroll
  for (int off = 1; off < 64; off <<= 1) mv += __shfl_xor(mv, off);
  if (lane == 0) redi[wave] = mv;
  const float4* gi4 = (const float4*)gi_glob;
  float4 gir0 = make_float4(0.f, 0.f, 0.f, 0.f), gir1 = gir0;
  if (wave == 6) {
    size_t base1 = ((size_t)b * 512 + 1) * 96;
    gir0 = gi4[base1 + lane];
    if (lane < 32) gir1 = gi4[base1 + 64 + lane];
  }
  float g1r = 0.f; int a2r = 0;
  if (wave == 7 && lane < 10) g1r = g1_tab[(size_t)b * 10 + lane];
  if (wave == 7 && lane == 12) a2r = a2_tab[b];
  __syncthreads();
  if (tid == 0) {
    int s = 0;
    #pragma unroll
    for (int w = 0; w < 8; w++) s += redi[w];
    last_s = s - 1;
  }
  __syncthreads();
  const int last = last_s;

  // ---- t = 0: h0 = gru(x0, 0); also obs for t=1 (= h0/10) ----
  if (tid < 128) {
    int j = tid;
    const float* g0 = gi_glob + (size_t)b * 512 * 384;
    float ir = g0[j] + b_hh[j];
    float iz = g0[128 + j] + b_hh[128 + j];
    float in_ = g0[256 + j];
    float hn = b_hh[256 + j];
    float r  = 1.0f / (1.0f + expf(-ir));
    float zz = 1.0f / (1.0f + expf(-iz));
    float n  = tanhf(in_ + r * hn);
    float hnew = (1.0f - zz) * n;
    hbuf[j] = hnew; ring2[0][j] = hnew; ring2[10][j] = hnew;
    obs[j] = hnew / 10.0f;
    if (0 == last) lastbuf[j] = hnew;
  }
  __syncthreads();

  // ---- t = 1..511 ----
  #pragma unroll 1
  for (int t = 1; t < T_; t++) {
    const int sn = (t + 9) % 10;   // slot of h_{t-1}
    if (tid < 384) {
      // ---- yc[sn] = W_hh · h_{t-1} ----
      const float4* hb4 = (const float4*)hbuf;
      float4 a0 = make_float4(0.f, 0.f, 0.f, 0.f), a1v = a0, a2v = a0, a3v = a0;
      #pragma unroll
      for (int c = 0; c < 8; c++) {
        float4 h4 = hb4[4 * c + qk];
        a0.x += wr[0][c].x * h4.x; a0.y += wr[0][c].y * h4.y; a0.z += wr[0][c].z * h4.z; a0.w += wr[0][c].w * h4.w;
        a1v.x += wr[1][c].x * h4.x; a1v.y += wr[1][c].y * h4.y; a1v.z += wr[1][c].z * h4.z; a1v.w += wr[1][c].w * h4.w;
        a2v.x += wr[2][c].x * h4.x; a2v.y += wr[2][c].y * h4.y; a2v.z += wr[2][c].z * h4.z; a2v.w += wr[2][c].w * h4.w;
        a3v.x += wr[3][c].x * h4.x; a3v.y += wr[3][c].y * h4.y; a3v.z += wr[3][c].z * h4.z; a3v.w += wr[3][c].w * h4.w;
      }
      float s0  = (a0.x + a0.y) + (a0.z + a0.w);
      float s1v = (a1v.x + a1v.y) + (a1v.z + a1v.w);
      float s2v = (a2v.x + a2v.y) + (a2v.z + a2v.w);
      float s3v = (a3v.x + a3v.y) + (a3v.z + a3v.w);
      s0  = dpp_add_xor2(dpp_add_xor1(s0));
      s1v = dpp_add_xor2(dpp_add_xor1(s1v));
      s2v = dpp_add_xor2(dpp_add_xor1(s2v));
      s3v = dpp_add_xor2(dpp_add_xor1(s3v));
      float my = (qk == 0) ? s0 : (qk == 1) ? s1v : (qk == 2) ? s2v : s3v;
      yc[sn][q + 96 * qk] = my;
    } else if (wave == 6) {
      float4 g0 = gir0;
      g0.x += bhh4a.x; g0.y += bhh4a.y; g0.z += bhh4a.z; g0.w += bhh4a.w;
      ((float4*)ghi)[lane] = g0;
      if (lane < 32) ((float4*)ghi)[64 + lane] = gir1;
      if (lane < 32)
        *(float4*)(out + BH_ + ((size_t)b * 512 + (t - 1)) * 128 + 4 * lane) =
            *(const float4*)(hbuf + 4 * lane);
      if (t < 511) {
        size_t basep = ((size_t)b * 512 + t + 1) * 96;
        gir0 = gi4[basep + lane];
        if (lane < 32) gir1 = gi4[basep + 64 + lane];
      }
      {
        int m = lane >> 1, kc = lane & 1;
        float ax = 0.f, ay = 0.f, az = 0.f, aw = 0.f;
        #pragma unroll
        for (int c = 0; c < 16; c++) {
          float4 o4 = ((const float4*)obs)[16 * kc + c];
          ax += w1reg[c].x * o4.x; ay += w1reg[c].y * o4.y;
          az += w1reg[c].z * o4.z; aw += w1reg[c].w * o4.w;
        }
        float d = (ax + ay) + (az + aw);
        d = dpp_add_xor1(d);
        if (kc == 0) z1buf[m] = tanhf(d + b1s[m]);
      }
      if (lane < 40) {
        int a = lane >> 2, k2 = lane & 3;
        int m0 = 8 * k2;
        float4 z4a = ((const float4*)(z1buf + m0))[0], z4b = ((const float4*)(z1buf + m0))[1];
        float4 wa = ((const float4*)(&w2buf[a][m0]))[0], wb = ((const float4*)(&w2buf[a][m0]))[1];
        float p = z4a.x * wa.x + z4a.y * wa.y + z4a.z * wa.z + z4a.w * wa.w
                + z4b.x * wb.x + z4b.y * wb.y + z4b.z * wb.z + z4b.w * wb.w;
        p = dpp_add_xor2(dpp_add_xor1(p));
        if (k2 == 0) pl2[a].x = p + b2s[a];
      }
    } else { // wave 7
      if (lane < 10) g1buf[lane] = g1r;
      if (lane == 12) a2s_lds = a2r;
      if (t < 511) {
        if (lane < 10) g1r = g1_tab[((size_t)t * 256 + b) * 10 + lane];
        if (lane == 12) a2r = a2_tab[(size_t)t * 256 + b];
      }
      {
        int m = 32 + (lane >> 1), kc = lane & 1;
        float ax = 0.f, ay = 0.f, az = 0.f, aw = 0.f;
        #pragma unroll
        for (int c = 0; c < 16; c++) {
          float4 o4 = ((const float4*)obs)[16 * kc + c];
          ax += w1reg[c].x * o4.x; ay += w1reg[c].y * o4.y;
          az += w1reg[c].z * o4.z; aw += w1reg[c].w * o4.w;
        }
        float d = (ax + ay) + (az + aw);
        d = dpp_add_xor1(d);
        if (kc == 0) z1buf[m] = tanhf(d + b1s[m]);
      }
      if (lane < 40) {
        int a = lane >> 2, k2 = lane & 3;
        int m0 = 32 + 8 * k2;
        float4 z4a = ((const float4*)(z1buf + m0))[0], z4b = ((const float4*)(z1buf + m0))[1];
        float4 wa = ((const float4*)(&w2buf[a][m0]))[0], wb = ((const float4*)(&w2buf[a][m0]))[1];
        float p = z4a.x * wa.x + z4a.y * wa.y + z4a.z * wa.z + z4a.w * wa.w
                + z4b.x * wb.x + z4b.y * wb.y + z4b.z * wb.z + z4b.w * wb.w;
        p = dpp_add_xor2(dpp_add_xor1(p));
        if (k2 == 0) pl2[a].y = p + g1buf[a];
      }
    }
    bar_lds();   // ycache/ghi/pl2/a2s ready

    if (tid < 128) {
      float best = 0.f; int bi = 0;
      #pragma unroll
      for (int a = 0; a < 10; a++) {
        float2 pv = pl2[a];
        float v = pv.x + pv.y;
        if (a == 0 || v > best) { best = v; bi = a; }
      }
      const int s1 = (t + bi) % 10;
      const int s2 = (t + a2s_lds) % 10;
      int j = tid;
      float gh1 = 0.5f * (0.5f * (yc[s1][j]       + yc[s2][j]))       + 0.5f * yc[sn][j];
      float gh2 = 0.5f * (0.5f * (yc[s1][128 + j] + yc[s2][128 + j])) + 0.5f * yc[sn][128 + j];
      float gh3 = bhh3s[j] + 0.5f * (0.5f * (yc[s1][256 + j] + yc[s2][256 + j])) + 0.5f * yc[sn][256 + j];
      float r  = 1.0f / (1.0f + expf(-(ghi[j] + gh1)));
      float zz = 1.0f / (1.0f + expf(-(ghi[128 + j] + gh2)));
      float n  = tanhf(ghi[256 + j] + r * gh3);
      float hw = 0.5f * ((ring2[s1][j] + ring2[s2][j]) * 0.5f) + 0.5f * hbuf[j];
      float hnew = (1.0f - zz) * n + zz * hw;
      hbuf[j] = hnew;
      ring2[t % 10][j] = hnew;
      ring2[t % 10 + 10][j] = hnew;
      if (t == last) lastbuf[j] = hnew;
      int base = (t + 1) % 10;
      float s = 0.f;
      #pragma unroll
      for (int a = 0; a < 9; a++) s += ring2[base + a][j];
      s += hnew;
      obs[j] = s / 10.0f;
    }
    bar_lds();   // hbuf/ring2/obs ready for next step
  }
  if (tid < 128) {
    out[(size_t)b * H_ + tid] = lastbuf[tid];
    out[BH_ + ((size_t)b * 512 + 511) * 128 + tid] = hbuf[tid];  // h_511
  }
}

extern "C" void kernel_launch(void* const* d_in, const int* in_sizes, int n_in,
                              void* d_out, int out_size, void* d_ws, size_t ws_size,
                              hipStream_t stream) {
  (void)in_sizes; (void)n_in; (void)out_size; (void)ws_size;
  const float* x     = (const float*)d_in[0];
  const int*   mask  = (const int*)d_in[1];
  const float* w_ih  = (const float*)d_in[2];
  const float* w_hh  = (const float*)d_in[3];
  const float* b_ih  = (const float*)d_in[4];
  const float* b_hh  = (const float*)d_in[5];
  const float* a1w1  = (const float*)d_in[6];
  const float* a1b1  = (const float*)d_in[7];
  const float* a1w2  = (const float*)d_in[8];
  const float* a1b2  = (const float*)d_in[9];
  const float* a2w1  = (const float*)d_in[10];
  const float* a2b1  = (const float*)d_in[11];
  const float* a2w2  = (const float*)d_in[12];
  const float* a2b2  = (const float*)d_in[13];
  float* out = (float*)d_out;

  // workspace: gi table (201.3 MB) | g1 (5.2 MB) | keys | a2 actions
  float*    gi       = (float*)d_ws;
  float*    g1       = gi + (size_t)131072 * 384;
  unsigned* keys_tab = (unsigned*)(g1 + NG);
  int*      a2_tab   = (int*)(keys_tab + 2048);

  p0_keys<<<4, 256, 0, stream>>>(keys_tab);
  p3_gumbel<<<5110, 256, 0, stream>>>(keys_tab, g1);
  p2_a2<<<4088, 256, 0, stream>>>(x, a2w1, a2b1, a2w2, a2b2, keys_tab, a2_tab);
  gemm_tiled<<<3072, 256, 0, stream>>>(x, w_ih, b_ih, gi);
  seq_kernel<<<256, 512, 0, stream>>>(gi, mask, w_hh, b_hh,
                                      a1w1, a1b1, a1w2, a1b2, g1, a2_tab, out);
}

// Round 7
// 1085.731 us; speedup vs baseline: 2.7522x; 1.3727x over previous
//
#include <hip/hip_runtime.h>
#include <math.h>

// Problem constants: B=256, T=512, D=128, H=128 (3H=384), U=64, A=10, LAMDA=0.5
#define B_ 256
#define T_ 512
#define D_ 128
#define H_ 128
#define BH_ 32768      // B_*H_
#define NG 1308160     // 511*256*10 gumbels per agent

// LDS-ordering-only barrier: skips the vmcnt(0) drain __syncthreads() forces.
__device__ __forceinline__ void bar_lds() {
  asm volatile("s_waitcnt lgkmcnt(0)\n\ts_barrier" ::: "memory");
}

// quad reductions on the VALU pipe (DPP), not the LDS pipe
__device__ __forceinline__ float dpp_add_xor1(float v) {
  int r = __builtin_amdgcn_update_dpp(0, __float_as_int(v), 0xB1, 0xF, 0xF, true);
  return v + __int_as_float(r);
}
__device__ __forceinline__ float dpp_add_xor2(float v) {
  int r = __builtin_amdgcn_update_dpp(0, __float_as_int(v), 0x4E, 0xF, 0xF, true);
  return v + __int_as_float(r);
}

// fast transcendentals (v_exp/v_rcp based, no div, no branches; ~3 ulp)
__device__ __forceinline__ float frcp(float x) { return __builtin_amdgcn_rcpf(x); }
__device__ __forceinline__ float fsigmoid(float x) { return frcp(1.0f + __expf(-x)); }
__device__ __forceinline__ float ftanh_(float x) { return 1.0f - 2.0f * frcp(1.0f + __expf(2.0f * x)); }

// ---------------- threefry2x32 (exact JAX semantics) ----------------
__device__ __forceinline__ void tf2x32(unsigned k0, unsigned k1, unsigned x0, unsigned x1,
                                       unsigned& o0, unsigned& o1) {
  unsigned k2 = k0 ^ k1 ^ 0x1BD11BDAu;
  unsigned v0 = x0 + k0, v1 = x1 + k1;
#define TFR(r) { v0 += v1; v1 = (v1 << (r)) | (v1 >> (32 - (r))); v1 ^= v0; }
  TFR(13) TFR(15) TFR(26) TFR(6)   v0 += k1; v1 += k2 + 1u;
  TFR(17) TFR(29) TFR(16) TFR(24)  v0 += k2; v1 += k0 + 2u;
  TFR(13) TFR(15) TFR(26) TFR(6)   v0 += k0; v1 += k1 + 3u;
  TFR(17) TFR(29) TFR(16) TFR(24)  v0 += k1; v1 += k2 + 4u;
  TFR(13) TFR(15) TFR(26) TFR(6)   v0 += k2; v1 += k0 + 5u;
#undef TFR
  o0 = v0; o1 = v1;
}

__device__ __forceinline__ float gumbel_f(unsigned bits) {
  const float tiny = 1.17549435e-38f;
  float u = __uint_as_float((bits >> 9) | 0x3f800000u) - 1.0f;
  u = u + tiny;
  u = fmaxf(tiny, u);
  return -__logf(-__logf(u));
}

// ---------------- P0: split keys (jax_threefry_partitionable=True) ----------------
__global__ void p0_keys(unsigned* __restrict__ keys_tab) {
  int i = blockIdx.x * blockDim.x + threadIdx.x;
  if (i >= 1024) return;
  unsigned o0, o1;
  tf2x32(0u, 42u, 0u, (unsigned)i, o0, o1);
  keys_tab[2 * i] = o0; keys_tab[2 * i + 1] = o1;
}

// ---------------- G: tiled fp32 GEMM, N=448 (384 gi cols + 64 a2-hidden cols) ----------
// Block tile 256m x 64n, 256 threads, micro 16m x 4n, K staged in 4 chunks of 32.
// nb==6 reads a2w1/a2b1, applies fast tanh, writes z table [M][64].
#define SX 264
#define SW 72
__global__ __launch_bounds__(256, 4) void gemm_tiled(
    const float* __restrict__ x, const float* __restrict__ w_ih,
    const float* __restrict__ b_ih, const float* __restrict__ a2w1,
    const float* __restrict__ a2b1, float* __restrict__ gi, float* __restrict__ zt) {
  __shared__ __align__(16) float Xs[32 * SX];
  __shared__ __align__(16) float Ws[32 * SW];
  const int tid = threadIdx.x;
  const int mb = blockIdx.x & 511;          // 512 m-tiles
  const int nb = blockIdx.x >> 9;           // 0..6
  const bool isz = (nb == 6);
  const size_t m0 = (size_t)mb * 256;
  const int n0 = isz ? 0 : nb * 64;
  const float* wsrc = isz ? a2w1 : w_ih;
  const float* bsrc = isz ? a2b1 : b_ih;
  const int mt = tid >> 4;                  // 0..15 -> rows mt*16..+15
  const int nt = tid & 15;                  // 0..15 -> cols nt*4..+3
  const int kg = tid >> 5;                  // staging: k-group 0..7
  const int ri = tid & 31;                  // staging: row-in-pass

  float acc[16][4];
  #pragma unroll
  for (int i = 0; i < 16; i++)
    #pragma unroll
    for (int j = 0; j < 4; j++) acc[i][j] = 0.f;

  #pragma unroll 1
  for (int kc = 0; kc < 4; kc++) {
    const int k0 = kc * 32;
    __syncthreads();
    #pragma unroll
    for (int p = 0; p < 8; p++) {
      int row = ri + 32 * p;
      float4 v = *(const float4*)(x + (m0 + row) * 128 + k0 + 4 * kg);
      Xs[(4 * kg + 0) * SX + row] = v.x;
      Xs[(4 * kg + 1) * SX + row] = v.y;
      Xs[(4 * kg + 2) * SX + row] = v.z;
      Xs[(4 * kg + 3) * SX + row] = v.w;
    }
    #pragma unroll
    for (int p = 0; p < 2; p++) {
      int n = ri + 32 * p;
      float4 v = *(const float4*)(wsrc + (size_t)(n0 + n) * 128 + k0 + 4 * kg);
      Ws[(4 * kg + 0) * SW + n] = v.x;
      Ws[(4 * kg + 1) * SW + n] = v.y;
      Ws[(4 * kg + 2) * SW + n] = v.z;
      Ws[(4 * kg + 3) * SW + n] = v.w;
    }
    __syncthreads();
    #pragma unroll 4
    for (int kk = 0; kk < 32; kk++) {
      const float* xrow = Xs + kk * SX + mt * 16;
      float4 xa0 = ((const float4*)xrow)[0];
      float4 xa1 = ((const float4*)xrow)[1];
      float4 xa2 = ((const float4*)xrow)[2];
      float4 xa3 = ((const float4*)xrow)[3];
      float4 wv = *(const float4*)(Ws + kk * SW + nt * 4);
      float xv[16] = {xa0.x, xa0.y, xa0.z, xa0.w, xa1.x, xa1.y, xa1.z, xa1.w,
                      xa2.x, xa2.y, xa2.z, xa2.w, xa3.x, xa3.y, xa3.z, xa3.w};
      #pragma unroll
      for (int i = 0; i < 16; i++) {
        acc[i][0] += xv[i] * wv.x;
        acc[i][1] += xv[i] * wv.y;
        acc[i][2] += xv[i] * wv.z;
        acc[i][3] += xv[i] * wv.w;
      }
    }
  }
  float4 bias = *(const float4*)(bsrc + n0 + nt * 4);
  if (!isz) {
    #pragma unroll
    for (int i = 0; i < 16; i++) {
      float4 o;
      o.x = acc[i][0] + bias.x; o.y = acc[i][1] + bias.y;
      o.z = acc[i][2] + bias.z; o.w = acc[i][3] + bias.w;
      size_t m = m0 + (size_t)mt * 16 + i;
      *(float4*)(gi + m * 384 + n0 + nt * 4) = o;
    }
  } else {
    #pragma unroll
    for (int i = 0; i < 16; i++) {
      float4 o;
      o.x = ftanh_(acc[i][0] + bias.x); o.y = ftanh_(acc[i][1] + bias.y);
      o.z = ftanh_(acc[i][2] + bias.z); o.w = ftanh_(acc[i][3] + bias.w);
      size_t m = m0 + (size_t)mt * 16 + i;
      *(float4*)(zt + m * 64 + nt * 4) = o;
    }
  }
}

// ---------------- SAMP: a2 logits+gumbel+argmax AND g1 gumbel table ----------------
// block = one t (511 blocks); wave per sample, z prefetch pipelined.
__global__ __launch_bounds__(256) void sampler(
    const float* __restrict__ zt, const float* __restrict__ w2,
    const float* __restrict__ b2, const unsigned* __restrict__ keys_tab,
    float* __restrict__ g1, int* __restrict__ a2_tab) {
  __shared__ __align__(16) float w2s[10][64];
  __shared__ float b2s[10];
  __shared__ __align__(16) float zs[4][64];
  const int tid = threadIdx.x, w = tid >> 6, lane = tid & 63;
  const int t = blockIdx.x + 1;
  for (int i = tid; i < 640; i += 256) w2s[i >> 6][i & 63] = w2[i];
  if (tid < 10) b2s[tid] = b2[tid];
  __syncthreads();
  const unsigned k0a = keys_tab[2 * (2 * t + 1)], k1a = keys_tab[2 * (2 * t + 1) + 1];
  const unsigned k0g = keys_tab[2 * (2 * t)],     k1g = keys_tab[2 * (2 * t) + 1];
  const int a = lane & 15, kc = lane >> 4;
  float zr = zt[((size_t)w * 512 + t) * 64 + lane];   // b = w (it=0)
  #pragma unroll 1
  for (int it = 0; it < 64; it++) {
    const int b = 4 * it + w;
    zs[w][lane] = zr;
    if (it < 63) zr = zt[((size_t)(b + 4) * 512 + t) * 64 + lane];
    float p = 0.f;
    if (a < 10) {
      const float4* zp = (const float4*)(&zs[w][16 * kc]);
      const float4* wp = (const float4*)(&w2s[a][16 * kc]);
      #pragma unroll
      for (int c = 0; c < 4; c++) {
        float4 zv = zp[c], w4 = wp[c];
        p += w4.x * zv.x + w4.y * zv.y + w4.z * zv.z + w4.w * zv.w;
      }
    }
    p += __shfl_xor(p, 16);
    p += __shfl_xor(p, 32);
    float val = -3.0e38f;
    if (a < 10 && kc == 0) {
      unsigned o0, o1;
      tf2x32(k0a, k1a, 0u, (unsigned)(b * 10 + a), o0, o1);
      val = (p + b2s[a]) + gumbel_f(o0 ^ o1);
      tf2x32(k0g, k1g, 0u, (unsigned)(b * 10 + a), o0, o1);
      g1[((size_t)(t - 1) * 256 + b) * 10 + a] = gumbel_f(o0 ^ o1);
    }
    float best = 0.f; int bi = 0;
    #pragma unroll
    for (int aa = 0; aa < 10; aa++) {
      float v = __shfl(val, aa);
      if (aa == 0 || v > best) { best = v; bi = aa; }
    }
    if (lane == 0) a2_tab[(size_t)(t - 1) * 256 + b] = bi;
  }
}

// ---------------- S: sequential per-batch kernel (1 block = 1 batch elem) ----------------
__global__ __launch_bounds__(512, 2) void seq_kernel(
    const float* __restrict__ gi_glob, const int* __restrict__ mask,
    const float* __restrict__ w_hh, const float* __restrict__ b_hh,
    const float* __restrict__ a1w1, const float* __restrict__ a1b1,
    const float* __restrict__ a1w2, const float* __restrict__ a1b2,
    const float* __restrict__ g1_tab, const int* __restrict__ a2_tab,
    float* __restrict__ out) {
  __shared__ __align__(16) float ring2[20][128];  // doubled ring: h_s at [s%10] and [s%10+10]
  __shared__ __align__(16) float yc[10][384];     // yc[s] = W_hh · ring[s]
  __shared__ __align__(16) float hbuf[128];       // h_{t-1}
  __shared__ __align__(16) float ghi[384];        // staged gi[b][t] (+b_hh on rows 0..255)
  __shared__ __align__(16) float obs[128];        // mean of ring (computed in gates phase)
  __shared__ __align__(16) float z1buf[64];
  __shared__ __align__(16) float lastbuf[128];
  __shared__ __align__(16) float w2buf[10][64];
  __shared__ float bhh3s[128];                    // b_hh rows 256..383 (n-gate)
  __shared__ float b1s[64], b2s[10];
  __shared__ float g1buf[10];
  __shared__ float2 pl2[16];
  __shared__ int a2s_lds;
  __shared__ int redi[8];
  __shared__ int last_s;

  const int tid = threadIdx.x;
  const int wave = tid >> 6, lane = tid & 63;
  const int b = blockIdx.x;

  // ---- register-resident W_hh for waves 0-5: rows 4q+i, k-quad qk ----
  float4 wr[4][8];
  const int q = tid >> 2, qk = tid & 3;
  if (tid < 384) {
    #pragma unroll
    for (int i = 0; i < 4; i++) {
      const float* basep = w_hh + (size_t)(4 * q + i) * 128 + 4 * qk;
      #pragma unroll
      for (int c = 0; c < 8; c++) wr[i][c] = *(const float4*)(basep + 16 * c);
    }
  }
  // ---- register-resident a1w1 for waves 6/7 ----
  float4 w1reg[16];
  float4 bhh4a = make_float4(0.f, 0.f, 0.f, 0.f);
  if (wave >= 6) {
    int m = ((wave - 6) << 5) + (lane >> 1);
    int kc = lane & 1;
    const float4* wp = (const float4*)(a1w1 + (size_t)m * 128 + 64 * kc);
    #pragma unroll
    for (int c = 0; c < 16; c++) w1reg[c] = wp[c];
  }
  if (wave == 6) bhh4a = ((const float4*)b_hh)[lane];   // rows 4*lane..+3 (0..255)

  // ---- LDS init ----
  for (int idx = tid; idx < 2560; idx += 512) ((float*)ring2)[idx] = 0.f;
  for (int idx = tid; idx < 3840; idx += 512) ((float*)yc)[idx] = 0.f;
  for (int idx = tid; idx < 640; idx += 512) w2buf[idx >> 6][idx & 63] = a1w2[idx];
  if (tid < 128) bhh3s[tid] = b_hh[256 + tid];
  if (tid < 64) b1s[tid] = a1b1[tid];
  if (tid < 10) b2s[tid] = a1b2[tid];
  int mv = mask[(size_t)b * T_ + tid];
  #pragma unroll
  for (int off = 1; off < 64; off <<= 1) mv += __shfl_xor(mv, off);
  if (lane == 0) redi[wave] = mv;
  const float4* gi4 = (const float4*)gi_glob;
  float4 gir0 = make_float4(0.f, 0.f, 0.f, 0.f), gir1 = gir0;
  if (wave == 6) {
    size_t base1 = ((size_t)b * 512 + 1) * 96;
    gir0 = gi4[base1 + lane];
    if (lane < 32) gir1 = gi4[base1 + 64 + lane];
  }
  float g1r = 0.f; int a2r = 0;
  if (wave == 7 && lane < 10) g1r = g1_tab[(size_t)b * 10 + lane];
  if (wave == 7 && lane == 12) a2r = a2_tab[b];
  __syncthreads();
  if (tid == 0) {
    int s = 0;
    #pragma unroll
    for (int w = 0; w < 8; w++) s += redi[w];
    last_s = s - 1;
  }
  __syncthreads();
  const int last = last_s;

  // ---- t = 0: h0 = gru(x0, 0); obs for t=1 ----
  if (tid < 128) {
    int j = tid;
    const float* g0 = gi_glob + (size_t)b * 512 * 384;
    float r  = fsigmoid(g0[j] + b_hh[j]);
    float zz = fsigmoid(g0[128 + j] + b_hh[128 + j]);
    float n  = ftanh_(g0[256 + j] + r * b_hh[256 + j]);
    float hnew = (1.0f - zz) * n;
    hbuf[j] = hnew; ring2[0][j] = hnew; ring2[10][j] = hnew;
    obs[j] = hnew / 10.0f;
    out[BH_ + ((size_t)b * 512) * 128 + j] = hnew;
    if (0 == last) lastbuf[j] = hnew;
  }
  __syncthreads();

  // ---- t = 1..511 ----
  #pragma unroll 1
  for (int t = 1; t < T_; t++) {
    const int sn = (t + 9) % 10;   // slot of h_{t-1}
    if (tid < 384) {
      // ---- yc[sn] = W_hh · h_{t-1}, rows 4q..4q+3 ----
      const float4* hb4 = (const float4*)hbuf;
      float4 a0 = make_float4(0.f, 0.f, 0.f, 0.f), a1v = a0, a2v = a0, a3v = a0;
      #pragma unroll
      for (int c = 0; c < 8; c++) {
        float4 h4 = hb4[4 * c + qk];
        a0.x += wr[0][c].x * h4.x; a0.y += wr[0][c].y * h4.y; a0.z += wr[0][c].z * h4.z; a0.w += wr[0][c].w * h4.w;
        a1v.x += wr[1][c].x * h4.x; a1v.y += wr[1][c].y * h4.y; a1v.z += wr[1][c].z * h4.z; a1v.w += wr[1][c].w * h4.w;
        a2v.x += wr[2][c].x * h4.x; a2v.y += wr[2][c].y * h4.y; a2v.z += wr[2][c].z * h4.z; a2v.w += wr[2][c].w * h4.w;
        a3v.x += wr[3][c].x * h4.x; a3v.y += wr[3][c].y * h4.y; a3v.z += wr[3][c].z * h4.z; a3v.w += wr[3][c].w * h4.w;
      }
      float s0  = (a0.x + a0.y) + (a0.z + a0.w);
      float s1v = (a1v.x + a1v.y) + (a1v.z + a1v.w);
      float s2v = (a2v.x + a2v.y) + (a2v.z + a2v.w);
      float s3v = (a3v.x + a3v.y) + (a3v.z + a3v.w);
      s0  = dpp_add_xor2(dpp_add_xor1(s0));
      s1v = dpp_add_xor2(dpp_add_xor1(s1v));
      s2v = dpp_add_xor2(dpp_add_xor1(s2v));
      s3v = dpp_add_xor2(dpp_add_xor1(s3v));
      float my = (qk == 0) ? s0 : (qk == 1) ? s1v : (qk == 2) ? s2v : s3v;
      yc[sn][4 * q + qk] = my;        // addr = tid -> conflict-free
    } else if (wave == 6) {
      float4 g0 = gir0;
      g0.x += bhh4a.x; g0.y += bhh4a.y; g0.z += bhh4a.z; g0.w += bhh4a.w;
      ((float4*)ghi)[lane] = g0;
      if (lane < 32) ((float4*)ghi)[64 + lane] = gir1;
      if (t < 511) {
        size_t basep = ((size_t)b * 512 + t + 1) * 96;
        gir0 = gi4[basep + lane];
        if (lane < 32) gir1 = gi4[basep + 64 + lane];
      }
      {
        int m = lane >> 1, kc = lane & 1;
        float ax = 0.f, ay = 0.f, az = 0.f, aw = 0.f;
        #pragma unroll
        for (int c = 0; c < 16; c++) {
          float4 o4 = ((const float4*)obs)[16 * kc + c];
          ax += w1reg[c].x * o4.x; ay += w1reg[c].y * o4.y;
          az += w1reg[c].z * o4.z; aw += w1reg[c].w * o4.w;
        }
        float d = (ax + ay) + (az + aw);
        d = dpp_add_xor1(d);
        if (kc == 0) z1buf[m] = ftanh_(d + b1s[m]);
      }
      if (lane < 40) {
        int a = lane >> 2, k2 = lane & 3;
        int m0 = 8 * k2;
        float4 z4a = ((const float4*)(z1buf + m0))[0], z4b = ((const float4*)(z1buf + m0))[1];
        float4 wa = ((const float4*)(&w2buf[a][m0]))[0], wb = ((const float4*)(&w2buf[a][m0]))[1];
        float p = z4a.x * wa.x + z4a.y * wa.y + z4a.z * wa.z + z4a.w * wa.w
                + z4b.x * wb.x + z4b.y * wb.y + z4b.z * wb.z + z4b.w * wb.w;
        p = dpp_add_xor2(dpp_add_xor1(p));
        if (k2 == 0) pl2[a].x = p + b2s[a];
      }
    } else { // wave 7
      if (lane < 10) g1buf[lane] = g1r;
      if (lane == 12) a2s_lds = a2r;
      if (t < 511) {
        if (lane < 10) g1r = g1_tab[((size_t)t * 256 + b) * 10 + lane];
        if (lane == 12) a2r = a2_tab[(size_t)t * 256 + b];
      }
      {
        int m = 32 + (lane >> 1), kc = lane & 1;
        float ax = 0.f, ay = 0.f, az = 0.f, aw = 0.f;
        #pragma unroll
        for (int c = 0; c < 16; c++) {
          float4 o4 = ((const float4*)obs)[16 * kc + c];
          ax += w1reg[c].x * o4.x; ay += w1reg[c].y * o4.y;
          az += w1reg[c].z * o4.z; aw += w1reg[c].w * o4.w;
        }
        float d = (ax + ay) + (az + aw);
        d = dpp_add_xor1(d);
        if (kc == 0) z1buf[m] = ftanh_(d + b1s[m]);
      }
      if (lane < 40) {
        int a = lane >> 2, k2 = lane & 3;
        int m0 = 32 + 8 * k2;
        float4 z4a = ((const float4*)(z1buf + m0))[0], z4b = ((const float4*)(z1buf + m0))[1];
        float4 wa = ((const float4*)(&w2buf[a][m0]))[0], wb = ((const float4*)(&w2buf[a][m0]))[1];
        float p = z4a.x * wa.x + z4a.y * wa.y + z4a.z * wa.z + z4a.w * wa.w
                + z4b.x * wb.x + z4b.y * wb.y + z4b.z * wb.z + z4b.w * wb.w;
        p = dpp_add_xor2(dpp_add_xor1(p));
        if (k2 == 0) pl2[a].y = p + g1buf[a];
      }
    }
    bar_lds();   // ycache/ghi/pl2/a2s ready

    if (tid < 128) {
      float best = 0.f; int bi = 0;
      #pragma unroll
      for (int a = 0; a < 10; a++) {
        float2 pv = pl2[a];
        float v = pv.x + pv.y;
        if (a == 0 || v > best) { best = v; bi = a; }
      }
      const int s1 = (t + bi) % 10;
      const int s2 = (t + a2s_lds) % 10;
      int j = tid;
      float gh1 = 0.5f * (0.5f * (yc[s1][j]       + yc[s2][j]))       + 0.5f * yc[sn][j];
      float gh2 = 0.5f * (0.5f * (yc[s1][128 + j] + yc[s2][128 + j])) + 0.5f * yc[sn][128 + j];
      float gh3 = bhh3s[j] + 0.5f * (0.5f * (yc[s1][256 + j] + yc[s2][256 + j])) + 0.5f * yc[sn][256 + j];
      float r  = fsigmoid(ghi[j] + gh1);
      float zz = fsigmoid(ghi[128 + j] + gh2);
      float n  = ftanh_(ghi[256 + j] + r * gh3);
      float hw = 0.5f * ((ring2[s1][j] + ring2[s2][j]) * 0.5f) + 0.5f * hbuf[j];
      float hnew = (1.0f - zz) * n + zz * hw;
      hbuf[j] = hnew;
      ring2[t % 10][j] = hnew;
      ring2[t % 10 + 10][j] = hnew;
      out[BH_ + ((size_t)b * 512 + t) * 128 + j] = hnew;   // direct h store
      if (t == last) lastbuf[j] = hnew;
      int base = (t + 1) % 10;
      float s = 0.f;
      #pragma unroll
      for (int a = 0; a < 9; a++) s += ring2[base + a][j];
      s += hnew;
      obs[j] = s / 10.0f;
    }
    bar_lds();   // hbuf/ring2/obs ready for next step
  }
  if (tid < 128) out[(size_t)b * H_ + tid] = lastbuf[tid];
}

extern "C" void kernel_launch(void* const* d_in, const int* in_sizes, int n_in,
                              void* d_out, int out_size, void* d_ws, size_t ws_size,
                              hipStream_t stream) {
  (void)in_sizes; (void)n_in; (void)out_size; (void)ws_size;
  const float* x     = (const float*)d_in[0];
  const int*   mask  = (const int*)d_in[1];
  const float* w_ih  = (const float*)d_in[2];
  const float* w_hh  = (const float*)d_in[3];
  const float* b_ih  = (const float*)d_in[4];
  const float* b_hh  = (const float*)d_in[5];
  const float* a1w1  = (const float*)d_in[6];
  const float* a1b1  = (const float*)d_in[7];
  const float* a1w2  = (const float*)d_in[8];
  const float* a1b2  = (const float*)d_in[9];
  const float* a2w1  = (const float*)d_in[10];
  const float* a2b1  = (const float*)d_in[11];
  const float* a2w2  = (const float*)d_in[12];
  const float* a2b2  = (const float*)d_in[13];
  float* out = (float*)d_out;

  // workspace: gi (201.3 MB) | g1 (5.2 MB) | keys | a2_tab | z table (33.5 MB)
  float*    gi       = (float*)d_ws;
  float*    g1       = gi + (size_t)131072 * 384;
  unsigned* keys_tab = (unsigned*)(g1 + NG);
  int*      a2_tab   = (int*)(keys_tab + 2048);
  float*    zt       = (float*)(a2_tab + 130816);

  p0_keys<<<4, 256, 0, stream>>>(keys_tab);
  gemm_tiled<<<3584, 256, 0, stream>>>(x, w_ih, b_ih, a2w1, a2b1, gi, zt);
  sampler<<<511, 256, 0, stream>>>(zt, a2w2, a2b2, keys_tab, g1, a2_tab);
  seq_kernel<<<256, 512, 0, stream>>>(gi, mask, w_hh, b_hh,
                                      a1w1, a1b1, a1w2, a1b2, g1, a2_tab, out);
}